// Round 11
// baseline (623.841 us; speedup 1.0000x reference)
//
#include <hip/hip_runtime.h>
#include <hip/hip_fp16.h>

#define T_DIM 2048
#define D_DIM 256
#define K_CODES 512
#define N_ROWS 131072
#define Q_ELEMS 33554432
#define FMARGIN 2.0e-4f

typedef __attribute__((ext_vector_type(8))) _Float16 f16x8;
typedef __attribute__((ext_vector_type(8))) short s16x8;
typedef __attribute__((ext_vector_type(4))) float f32x4;

// ws layout (bytes) -- identical proven footprint (round 9/10):
// [0, 2048)        norms (512 f32, numpy-pairwise-exact)
// [2048, 18432)    bsums (2048 f64, main loss partials)
// [20480, 36864)   bitmap (4096 u32; bit = row needs exact rescan)
// [36864, 40960)   bsums2 (512 f64, xpose sum(x^2) partials)
// [40960, 303104)  e16: f16(512*e), k-granule: u16 idx = (k>>5)*8192+(d>>3)*256+(k&31)*8+(d&7)
// [303104, 67411968) x16: f16(x), k-granule per 64-row span:
//                  u16 idx = (n>>6)*16384 + (d>>3)*512 + (n&63)*8 + (d&7)

__device__ __forceinline__ float comb8(const float* r) {
  return ((r[0] + r[1]) + (r[2] + r[3])) + ((r[4] + r[5]) + (r[6] + r[7]));
}

__device__ __forceinline__ void gl_lds16(const void* g, void* l) {
  __builtin_amdgcn_global_load_lds(
      (const __attribute__((address_space(1))) unsigned int*)g,
      (__attribute__((address_space(3))) unsigned int*)l, 16, 0, 0);
}

__global__ __launch_bounds__(256) void vq_prep(const float* __restrict__ e,
                                               float* __restrict__ norms,
                                               unsigned short* __restrict__ e16) {
  __shared__ float srow[D_DIM];
  int k = blockIdx.x, t = threadIdx.x;
  float v = e[k * D_DIM + t];
  srow[t] = v;
  e16[(k >> 5) * 8192 + (t >> 3) * 256 + (k & 31) * 8 + (t & 7)] =
      __half_as_ushort(__float2half(512.0f * v));
  __syncthreads();
  if (t == 0) {
    float res[2];
    #pragma unroll
    for (int h = 0; h < 2; ++h) {
      float r[8];
      #pragma unroll
      for (int j = 0; j < 8; ++j) { float a = srow[h * 128 + j]; r[j] = __fmul_rn(a, a); }
      for (int i = 8; i < 128; i += 8)
        #pragma unroll
        for (int j = 0; j < 8; ++j) { float a = srow[h * 128 + i + j]; r[j] = __fadd_rn(r[j], __fmul_rn(a, a)); }
      res[h] = comb8(r);
    }
    norms[k] = __fadd_rn(res[0], res[1]);
  }
}

// x [B,D,T] fp32 -> x16 f16 k-granule + sum(x^2). 1KB-sequential reads,
// linear b128 writes.
__global__ __launch_bounds__(512, 1) void vq_xpose(const float* __restrict__ x,
                                                   unsigned short* __restrict__ x16,
                                                   double* __restrict__ bsums2) {
  __shared__ unsigned short tlu[32 * 2048];   // 128 KB: [kg 32][t 256][8 u16]
  __shared__ double dred[8];
  const int tx = threadIdx.x, blk = blockIdx.x;     // 512 = 64 b x 8 t-chunks
  const int b = blk >> 3, t0 = (blk & 7) * 256;
  const int w = tx >> 6, lane = tx & 63;

  float xsq = 0.f;
  #pragma unroll
  for (int g8 = 0; g8 < 4; ++g8) {
    unsigned short pk[4][8];
    #pragma unroll
    for (int dj = 0; dj < 8; ++dj) {
      int d = w * 32 + g8 * 8 + dj;
      float4 v = *(const float4*)(x + (size_t)(b * 256 + d) * 2048 + t0 + lane * 4);
      xsq = fmaf(v.x, v.x, xsq); xsq = fmaf(v.y, v.y, xsq);
      xsq = fmaf(v.z, v.z, xsq); xsq = fmaf(v.w, v.w, xsq);
      pk[0][dj] = __half_as_ushort(__float2half(v.x));
      pk[1][dj] = __half_as_ushort(__float2half(v.y));
      pk[2][dj] = __half_as_ushort(__float2half(v.z));
      pk[3][dj] = __half_as_ushort(__float2half(v.w));
    }
    int kg = w * 4 + g8;
    #pragma unroll
    for (int j = 0; j < 4; ++j)
      *(s16x8*)&tlu[kg * 2048 + (lane * 4 + j) * 8] = *(s16x8*)&pk[j][0];
  }
  __syncthreads();
  const size_t obase = (size_t)(b * 2048 + t0) * 256;
  #pragma unroll 4
  for (int i = 0; i < 16; ++i) {
    int q = tx + i * 512;
    s16x8 vv = *(const s16x8*)&tlu[((q >> 6) & 31) * 2048 + ((q >> 11) * 64 + (q & 63)) * 8];
    *(s16x8*)(x16 + obase + (size_t)q * 8) = vv;
  }
  double dv = (double)xsq;
  #pragma unroll
  for (int o = 32; o > 0; o >>= 1) dv += __shfl_down(dv, o, 64);
  if (lane == 0) dred[w] = dv;
  __syncthreads();
  if (tx == 0) {
    double s = 0.0;
    #pragma unroll
    for (int i = 0; i < 8; ++i) s += dred[i];
    bsums2[blk] = s;
  }
}

// T3 2-phase GEMM+argmin: A via Bu (reused), B depth-1 prefetch, ONE barrier
// per chunk. Top-2 fold only; flagged rows -> vq_fixup full rescan.
__global__ __launch_bounds__(256, 1) void vq_main(
    const float* __restrict__ norms, const unsigned short* __restrict__ e16,
    const unsigned short* __restrict__ x16, const float* __restrict__ e,
    float* __restrict__ out_q, float* __restrict__ out_idx,
    double* __restrict__ bsums, unsigned* __restrict__ bitmap) {
  __shared__ unsigned short Bu[2][8192];      // 32 KB: B dbuf; also A staging
  __shared__ float nlds[K_CODES];             // 2 KB
  __shared__ float wredm[2][64], wredm2[2][64];
  __shared__ int   wredi[2][64];
  __shared__ float rmin[64];
  __shared__ int   widx[64];
  __shared__ double dred[4];

  const int tx = threadIdx.x, blk = blockIdx.x;   // 2048 blocks x 64 rows
  const int lane = tx & 63, w = tx >> 6;
  const int wm = w & 1, wn = w >> 1;              // rows wm*32..+32, codes wn*16 of 32
  const int c = lane & 15, g = lane >> 4;

  nlds[tx] = norms[tx];
  nlds[tx + 256] = norms[tx + 256];

  // --- stage A (32 KB) through Bu, hoist fragments, then hand Bu to B pipeline
  #pragma unroll
  for (int i = 0; i < 8; ++i)
    gl_lds16(x16 + (size_t)blk * 16384 + i * 2048 + tx * 8, &Bu[0][0] + i * 2048 + w * 512);
  __syncthreads();                            // implicit vmcnt(0): A ready
  f16x8 af2[2][8];
  #pragma unroll
  for (int mi = 0; mi < 2; ++mi)
    #pragma unroll
    for (int ch = 0; ch < 8; ++ch)
      af2[mi][ch] = *(const f16x8*)(&Bu[0][0] + (ch * 4 + g) * 512 + (wm * 32 + mi * 16 + c) * 8);
  __syncthreads();                            // all waves done reading A
  #pragma unroll
  for (int i = 0; i < 4; ++i)                 // B0
    gl_lds16(e16 + i * 2048 + tx * 8, &Bu[0][i * 2048 + w * 512]);
  __syncthreads();                            // implicit vmcnt(0): B0 ready

  float m[8], m2[8];
  int id[8];
  #pragma unroll
  for (int si = 0; si < 8; ++si) { m[si] = 3.4e38f; m2[si] = 3.4e38f; id[si] = 0; }

  for (int it = 0; it < 16; ++it) {           // 32 codes per chunk
    if (it < 15) {                            // depth-1 prefetch, covered by compute
      #pragma unroll
      for (int i = 0; i < 4; ++i)
        gl_lds16(e16 + (size_t)(it + 1) * 8192 + i * 2048 + tx * 8,
                 &Bu[(it + 1) & 1][i * 2048 + w * 512]);
    }
    const unsigned short* bb = &Bu[it & 1][0];
    f32x4 acc[2];
    acc[0] = (f32x4){0.f, 0.f, 0.f, 0.f};
    acc[1] = (f32x4){0.f, 0.f, 0.f, 0.f};
    #pragma unroll
    for (int ch = 0; ch < 8; ++ch) {
      f16x8 bf = *(const f16x8*)&bb[(ch * 4 + g) * 256 + (wn * 16 + c) * 8];
      acc[0] = __builtin_amdgcn_mfma_f32_16x16x32_f16(af2[0][ch], bf, acc[0], 0, 0, 0);
      acc[1] = __builtin_amdgcn_mfma_f32_16x16x32_f16(af2[1][ch], bf, acc[1], 0, 0, 0);
    }
    int code = it * 32 + wn * 16 + c;
    float nrm = nlds[code];
    #pragma unroll
    for (int mi = 0; mi < 2; ++mi)
      #pragma unroll
      for (int q = 0; q < 4; ++q) {
        int si = mi * 4 + q;
        float sv = fmaf(-0.00390625f, acc[mi][q], nrm);   // nrm - 2*dot/512
        if (sv < m[si])       { m2[si] = m[si]; m[si] = sv; id[si] = code; }
        else if (sv < m2[si]) { m2[si] = sv; }
      }
    __syncthreads();   // drains prefetch (issued ~600cyc ago) + buffer handoff
  }

  // cross-lane (16 codes over c) top-2 butterfly; ascending-k tie -> lower id wins
  #pragma unroll
  for (int si = 0; si < 8; ++si) {
    float M = m[si], M2 = m2[si];
    int I = id[si];
    #pragma unroll
    for (int off = 1; off < 16; off <<= 1) {
      float om = __shfl_xor(M, off, 64), om2 = __shfl_xor(M2, off, 64);
      int oi = __shfl_xor(I, off, 64);
      float nm2 = fminf(fmaxf(M, om), fminf(M2, om2));
      if (om < M || (om == M && oi < I)) { M = om; I = oi; }
      M2 = nm2;
    }
    if (c == 0) {
      int row = wm * 32 + (si >> 2) * 16 + g * 4 + (si & 3);
      wredm[wn][row] = M; wredm2[wn][row] = M2; wredi[wn][row] = I;
    }
  }
  __syncthreads();

  float myrmin = 0.f;
  if (tx < 64) {
    float M = wredm[0][tx], M2 = wredm2[0][tx];
    int I = wredi[0][tx];
    float om = wredm[1][tx], om2 = wredm2[1][tx];
    int oi = wredi[1][tx];
    float nm2 = fminf(fmaxf(M, om), fminf(M2, om2));
    if (om < M || (om == M && oi < I)) { M = om; I = oi; }
    M2 = nm2;
    myrmin = M;
    widx[tx] = I;
    rmin[tx] = M;
    out_idx[(size_t)blk * 64 + tx] = (float)I;
    unsigned long long bm = __ballot(M2 - M <= FMARGIN);
    if (lane == 0) {
      bitmap[blk * 2] = (unsigned)bm;
      bitmap[blk * 2 + 1] = (unsigned)(bm >> 32);
    }
  }
  __syncthreads();

  // fused q-write: wave w writes rows [w*16, w*16+16) from e (L2-hot)
  #pragma unroll 4
  for (int i = 0; i < 16; ++i) {
    int row = w * 16 + i;
    int k = widx[row];
    float4 ev = *(const float4*)(e + (size_t)k * D_DIM + lane * 4);
    *(float4*)(out_q + ((size_t)blk * 64 + row) * D_DIM + lane * 4) = ev;
  }

  double dv = (tx < 64) ? (double)rmin[tx] : 0.0;
  #pragma unroll
  for (int o = 32; o > 0; o >>= 1) dv += __shfl_down(dv, o, 64);
  if (lane == 0) dred[w] = dv;
  __syncthreads();
  if (tx == 0) bsums[blk] = (dred[0] + dred[1]) + (dred[2] + dred[3]);
}

// Full exact rescan (wave-per-row, lane-parallel, numpy-replica) for flagged
// rows; rewrites idx + q row.
__global__ __launch_bounds__(64) void vq_fixup(
    const float* __restrict__ x, const float* __restrict__ e,
    const float* __restrict__ norms, const unsigned* __restrict__ bitmap,
    float* __restrict__ out_q, float* __restrict__ out_idx) {
  __shared__ float xrow[256];
  __shared__ float xr16[16];
  const int blk = blockIdx.x, lane = threadIdx.x;
  unsigned long long bm = (unsigned long long)bitmap[blk * 2] |
                          ((unsigned long long)bitmap[blk * 2 + 1] << 32);
  if (!bm) return;
  const int b = blk >> 5, t0 = (blk & 31) * 64;
  while (bm) {
    int row = __ffsll(bm) - 1; bm &= bm - 1;
    int trow = t0 + row;
    #pragma unroll
    for (int j = 0; j < 4; ++j)
      xrow[lane + 64 * j] = x[((size_t)(b * 256 + lane + 64 * j)) * 2048 + trow];
    asm volatile("s_waitcnt vmcnt(0) lgkmcnt(0)" ::: "memory");
    if (lane < 16) {   // exact numpy-pairwise ||x||^2
      int h = lane >> 3, jj = lane & 7;
      float a0 = xrow[h * 128 + jj];
      float r = __fmul_rn(a0, a0);
      for (int i = 1; i < 16; ++i) {
        float a = xrow[h * 128 + i * 8 + jj];
        r = __fadd_rn(r, __fmul_rn(a, a));
      }
      xr16[lane] = r;
    }
    asm volatile("s_waitcnt lgkmcnt(0)" ::: "memory");
    float xx = __fadd_rn(comb8(&xr16[0]), comb8(&xr16[8]));
    float am[8];
    #pragma unroll
    for (int cc = 0; cc < 8; ++cc) am[cc] = 0.f;
    const float* eb = e + (size_t)(lane * 8) * D_DIM;
    for (int d4 = 0; d4 < 64; ++d4) {
      float4 xv = *(const float4*)&xrow[d4 * 4];
      #pragma unroll
      for (int cc = 0; cc < 8; ++cc) {
        float4 ev = *(const float4*)(eb + (size_t)cc * D_DIM + d4 * 4);
        am[cc] = __fmaf_rn(xv.x, ev.x, am[cc]);
        am[cc] = __fmaf_rn(xv.y, ev.y, am[cc]);
        am[cc] = __fmaf_rn(xv.z, ev.z, am[cc]);
        am[cc] = __fmaf_rn(xv.w, ev.w, am[cc]);
      }
    }
    float lm = 3.4e38f; int lk = 0;
    #pragma unroll
    for (int cc = 0; cc < 8; ++cc) {
      int k = lane * 8 + cc;
      float t1 = __fadd_rn(xx, norms[k]);
      float sv = t1 - 2.0f * am[cc];
      if (sv < lm) { lm = sv; lk = k; }    // ascending -> first-min
    }
    #pragma unroll
    for (int off = 1; off < 64; off <<= 1) {
      float om = __shfl_xor(lm, off, 64);
      int oi = __shfl_xor(lk, off, 64);
      if (om < lm || (om == lm && oi < lk)) { lm = om; lk = oi; }
    }
    if (lane == 0) out_idx[(size_t)blk * 64 + row] = (float)lk;
    int wk = __shfl(lk, 0);
    float4 ev = *(const float4*)(e + (size_t)wk * D_DIM + lane * 4);
    *(float4*)(out_q + ((size_t)blk * 64 + row) * D_DIM + lane * 4) = ev;
  }
}

__global__ __launch_bounds__(256) void vq_final(const double* __restrict__ bs,
                                                const double* __restrict__ bs2,
                                                float* __restrict__ out_loss) {
  __shared__ double sred[4];
  int t = threadIdx.x;
  double s = 0.0;
  for (int i = t; i < 2048; i += 256) s += bs[i];
  for (int i = t; i < 512; i += 256) s += bs2[i];
  #pragma unroll
  for (int o = 32; o > 0; o >>= 1) s += __shfl_down(s, o, 64);
  if ((t & 63) == 0) sred[t >> 6] = s;
  __syncthreads();
  if (t == 0)
    out_loss[0] = (float)(0.25 * (((sred[0] + sred[1]) + (sred[2] + sred[3])) / (double)Q_ELEMS));
}

extern "C" void kernel_launch(void* const* d_in, const int* in_sizes, int n_in,
                              void* d_out, int out_size, void* d_ws, size_t ws_size,
                              hipStream_t stream) {
  const float* x = (const float*)d_in[0];
  const float* e = (const float*)d_in[1];
  float* out = (float*)d_out;
  float* out_q = out;
  float* out_loss = out + Q_ELEMS;
  float* out_idx = out + Q_ELEMS + 1;

  char* ws = (char*)d_ws;
  float* norms = (float*)ws;
  double* bsums = (double*)(ws + 2048);
  unsigned* bitmap = (unsigned*)(ws + 20480);
  double* bsums2 = (double*)(ws + 36864);
  unsigned short* e16 = (unsigned short*)(ws + 40960);
  unsigned short* x16 = (unsigned short*)(ws + 303104);

  vq_prep<<<K_CODES, 256, 0, stream>>>(e, norms, e16);
  vq_xpose<<<512, 512, 0, stream>>>(x, x16, bsums2);
  vq_main<<<N_ROWS / 64, 256, 0, stream>>>(norms, e16, x16, e, out_q, out_idx, bsums, bitmap);
  vq_fixup<<<N_ROWS / 64, 64, 0, stream>>>(x, e, norms, bitmap, out_q, out_idx);
  vq_final<<<1, 256, 0, stream>>>(bsums, bsums2, out_loss);
}

// Round 12
// 409.915 us; speedup vs baseline: 1.5219x; 1.5219x over previous
//
#include <hip/hip_runtime.h>
#include <hip/hip_fp16.h>

#define T_DIM 2048
#define D_DIM 256
#define K_CODES 512
#define N_ROWS 131072
#define Q_ELEMS 33554432
#define FMARGIN 2.0e-4f

typedef __attribute__((ext_vector_type(8))) _Float16 f16x8;
typedef __attribute__((ext_vector_type(8))) short s16x8;
typedef __attribute__((ext_vector_type(4))) float f32x4;

// ws layout (bytes) -- proven footprint (rounds 9-11):
// [0, 2048)        norms (512 f32, numpy-pairwise-exact)
// [2048, 18432)    bsums (2048 f64, main loss partials)
// [20480, 36864)   bitmap (4096 u32; bit = row flagged: pair-resolve OR rescan)
// [36864, 40960)   bsums2 (512 f64, xpose sum(x^2) partials)
// [40960, 303104)  e16: f16(512*e), k-granule: u16 idx = (k>>5)*8192+(d>>3)*256+(k&31)*8+(d&7)
// [303104, 67411968) x16: f16(x), k-granule per 64-row span
// Flag encoding in out_idx[n] (floats, exact): plain row -> I;
// pair -> I + 1024*(I2+1); needs-full-rescan -> I + 1024*1023.

__device__ __forceinline__ float comb8(const float* r) {
  return ((r[0] + r[1]) + (r[2] + r[3])) + ((r[4] + r[5]) + (r[6] + r[7]));
}

__device__ __forceinline__ void merge3(float& m, int& id, float& m2, int& id2, float& m3,
                                       float om, int oi, float om2, int oi2, float om3) {
  if (om < m || (om == m && oi < id)) {
    float tm = m; int ti = id; float tm2 = m2;
    m = om; id = oi;
    if (om2 < tm || (om2 == tm && oi2 < ti)) { m2 = om2; id2 = oi2; m3 = fminf(tm, om3); }
    else { m2 = tm; id2 = ti; m3 = fminf(tm2, om2); }
  } else {
    if (om < m2 || (om == m2 && oi < id2)) { float tm2 = m2; m2 = om; id2 = oi; m3 = fminf(tm2, om2); }
    else { m3 = fminf(m3, om); }
  }
}

__device__ __forceinline__ void gl_lds16(const void* g, void* l) {
  __builtin_amdgcn_global_load_lds(
      (const __attribute__((address_space(1))) unsigned int*)g,
      (__attribute__((address_space(3))) unsigned int*)l, 16, 0, 0);
}

__global__ __launch_bounds__(256) void vq_prep(const float* __restrict__ e,
                                               float* __restrict__ norms,
                                               unsigned short* __restrict__ e16) {
  __shared__ float srow[D_DIM];
  int k = blockIdx.x, t = threadIdx.x;
  float v = e[k * D_DIM + t];
  srow[t] = v;
  e16[(k >> 5) * 8192 + (t >> 3) * 256 + (k & 31) * 8 + (t & 7)] =
      __half_as_ushort(__float2half(512.0f * v));
  __syncthreads();
  if (t == 0) {
    float res[2];
    #pragma unroll
    for (int h = 0; h < 2; ++h) {
      float r[8];
      #pragma unroll
      for (int j = 0; j < 8; ++j) { float a = srow[h * 128 + j]; r[j] = __fmul_rn(a, a); }
      for (int i = 8; i < 128; i += 8)
        #pragma unroll
        for (int j = 0; j < 8; ++j) { float a = srow[h * 128 + i + j]; r[j] = __fadd_rn(r[j], __fmul_rn(a, a)); }
      res[h] = comb8(r);
    }
    norms[k] = __fadd_rn(res[0], res[1]);
  }
}

__global__ __launch_bounds__(512, 1) void vq_xpose(const float* __restrict__ x,
                                                   unsigned short* __restrict__ x16,
                                                   double* __restrict__ bsums2) {
  __shared__ unsigned short tlu[32 * 2048];
  __shared__ double dred[8];
  const int tx = threadIdx.x, blk = blockIdx.x;
  const int b = blk >> 3, t0 = (blk & 7) * 256;
  const int w = tx >> 6, lane = tx & 63;

  float xsq = 0.f;
  #pragma unroll
  for (int g8 = 0; g8 < 4; ++g8) {
    unsigned short pk[4][8];
    #pragma unroll
    for (int dj = 0; dj < 8; ++dj) {
      int d = w * 32 + g8 * 8 + dj;
      float4 v = *(const float4*)(x + (size_t)(b * 256 + d) * 2048 + t0 + lane * 4);
      xsq = fmaf(v.x, v.x, xsq); xsq = fmaf(v.y, v.y, xsq);
      xsq = fmaf(v.z, v.z, xsq); xsq = fmaf(v.w, v.w, xsq);
      pk[0][dj] = __half_as_ushort(__float2half(v.x));
      pk[1][dj] = __half_as_ushort(__float2half(v.y));
      pk[2][dj] = __half_as_ushort(__float2half(v.z));
      pk[3][dj] = __half_as_ushort(__float2half(v.w));
    }
    int kg = w * 4 + g8;
    #pragma unroll
    for (int j = 0; j < 4; ++j)
      *(s16x8*)&tlu[kg * 2048 + (lane * 4 + j) * 8] = *(s16x8*)&pk[j][0];
  }
  __syncthreads();
  const size_t obase = (size_t)(b * 2048 + t0) * 256;
  #pragma unroll 4
  for (int i = 0; i < 16; ++i) {
    int q = tx + i * 512;
    s16x8 vv = *(const s16x8*)&tlu[((q >> 6) & 31) * 2048 + ((q >> 11) * 64 + (q & 63)) * 8];
    *(s16x8*)(x16 + obase + (size_t)q * 8) = vv;
  }
  double dv = (double)xsq;
  #pragma unroll
  for (int o = 32; o > 0; o >>= 1) dv += __shfl_down(dv, o, 64);
  if (lane == 0) dred[w] = dv;
  __syncthreads();
  if (tx == 0) {
    double s = 0.0;
    #pragma unroll
    for (int i = 0; i < 8; ++i) s += dred[i];
    bsums2[blk] = s;
  }
}

// Round-11 T3 schedule (prefetch-first, ONE barrier/chunk) + round-10 top-3 fold.
__global__ __launch_bounds__(256, 1) void vq_main(
    const float* __restrict__ norms, const unsigned short* __restrict__ e16,
    const unsigned short* __restrict__ x16, const float* __restrict__ e,
    float* __restrict__ out_q, float* __restrict__ out_idx,
    double* __restrict__ bsums, unsigned* __restrict__ bitmap) {
  __shared__ unsigned short Bu[2][8192];      // 32 KB: B dbuf; also A staging
  __shared__ float nlds[K_CODES];
  __shared__ float wredm[2][64], wredm2[2][64], wredm3[2][64];
  __shared__ int   wredi[2][64], wredi2[2][64];
  __shared__ float rmin[64];
  __shared__ int   widx[64];
  __shared__ double dred[4];

  const int tx = threadIdx.x, blk = blockIdx.x;   // 2048 blocks x 64 rows
  const int lane = tx & 63, w = tx >> 6;
  const int wm = w & 1, wn = w >> 1;
  const int c = lane & 15, g = lane >> 4;

  nlds[tx] = norms[tx];
  nlds[tx + 256] = norms[tx + 256];

  // stage A through Bu, hoist fragments, hand Bu to B pipeline
  #pragma unroll
  for (int i = 0; i < 8; ++i)
    gl_lds16(x16 + (size_t)blk * 16384 + i * 2048 + tx * 8, &Bu[0][0] + i * 2048 + w * 512);
  __syncthreads();
  f16x8 af2[2][8];
  #pragma unroll
  for (int mi = 0; mi < 2; ++mi)
    #pragma unroll
    for (int ch = 0; ch < 8; ++ch)
      af2[mi][ch] = *(const f16x8*)(&Bu[0][0] + (ch * 4 + g) * 512 + (wm * 32 + mi * 16 + c) * 8);
  __syncthreads();
  #pragma unroll
  for (int i = 0; i < 4; ++i)
    gl_lds16(e16 + i * 2048 + tx * 8, &Bu[0][i * 2048 + w * 512]);
  __syncthreads();

  float m[8], m2[8], m3[8];
  int id[8], id2[8];
  #pragma unroll
  for (int si = 0; si < 8; ++si) { m[si] = 3.4e38f; m2[si] = 3.4e38f; m3[si] = 3.4e38f; id[si] = 0; id2[si] = 0; }

  for (int it = 0; it < 16; ++it) {
    if (it < 15) {
      #pragma unroll
      for (int i = 0; i < 4; ++i)
        gl_lds16(e16 + (size_t)(it + 1) * 8192 + i * 2048 + tx * 8,
                 &Bu[(it + 1) & 1][i * 2048 + w * 512]);
    }
    const unsigned short* bb = &Bu[it & 1][0];
    f32x4 acc[2];
    acc[0] = (f32x4){0.f, 0.f, 0.f, 0.f};
    acc[1] = (f32x4){0.f, 0.f, 0.f, 0.f};
    #pragma unroll
    for (int ch = 0; ch < 8; ++ch) {
      f16x8 bf = *(const f16x8*)&bb[(ch * 4 + g) * 256 + (wn * 16 + c) * 8];
      acc[0] = __builtin_amdgcn_mfma_f32_16x16x32_f16(af2[0][ch], bf, acc[0], 0, 0, 0);
      acc[1] = __builtin_amdgcn_mfma_f32_16x16x32_f16(af2[1][ch], bf, acc[1], 0, 0, 0);
    }
    int code = it * 32 + wn * 16 + c;
    float nrm = nlds[code];
    #pragma unroll
    for (int mi = 0; mi < 2; ++mi)
      #pragma unroll
      for (int q = 0; q < 4; ++q) {
        int si = mi * 4 + q;
        float sv = fmaf(-0.00390625f, acc[mi][q], nrm);   // nrm - 2*dot/512
        if (sv < m[si])       { m3[si] = m2[si]; m2[si] = m[si]; id2[si] = id[si]; m[si] = sv; id[si] = code; }
        else if (sv < m2[si]) { m3[si] = m2[si]; m2[si] = sv; id2[si] = code; }
        else if (sv < m3[si]) { m3[si] = sv; }
      }
    __syncthreads();   // drains prefetch (covered by compute) + buffer handoff
  }

  // cross-lane top-3 butterfly (16 codes over c)
  #pragma unroll
  for (int si = 0; si < 8; ++si) {
    float M = m[si], M2 = m2[si], M3 = m3[si];
    int I = id[si], I2 = id2[si];
    #pragma unroll
    for (int off = 1; off < 16; off <<= 1) {
      float om = __shfl_xor(M, off, 64), om2 = __shfl_xor(M2, off, 64), om3 = __shfl_xor(M3, off, 64);
      int oi = __shfl_xor(I, off, 64), oi2 = __shfl_xor(I2, off, 64);
      merge3(M, I, M2, I2, M3, om, oi, om2, oi2, om3);
    }
    if (c == 0) {
      int row = wm * 32 + (si >> 2) * 16 + g * 4 + (si & 3);
      wredm[wn][row] = M; wredm2[wn][row] = M2; wredm3[wn][row] = M3;
      wredi[wn][row] = I; wredi2[wn][row] = I2;
    }
  }
  __syncthreads();

  if (tx < 64) {
    float M = wredm[0][tx], M2 = wredm2[0][tx], M3 = wredm3[0][tx];
    int I = wredi[0][tx], I2 = wredi2[0][tx];
    merge3(M, I, M2, I2, M3, wredm[1][tx], wredi[1][tx], wredm2[1][tx], wredi2[1][tx], wredm3[1][tx]);
    rmin[tx] = M;
    widx[tx] = I;
    bool rescan = (M3 - M <= FMARGIN);
    bool pairf  = (M2 - M <= FMARGIN) && !rescan;
    int enc = I;
    if (pairf)  enc = I + 1024 * (I2 + 1);
    if (rescan) enc = I + 1024 * 1023;
    out_idx[(size_t)blk * 64 + tx] = (float)enc;
    unsigned long long bm = __ballot(pairf | rescan);
    if (lane == 0) {
      bitmap[blk * 2] = (unsigned)bm;
      bitmap[blk * 2 + 1] = (unsigned)(bm >> 32);
    }
  }
  __syncthreads();

  // fused q-write (approx idx; resolve/fixup rewrite their rows)
  #pragma unroll 4
  for (int i = 0; i < 16; ++i) {
    int row = w * 16 + i;
    int k = widx[row];
    float4 ev = *(const float4*)(e + (size_t)k * D_DIM + lane * 4);
    *(float4*)(out_q + ((size_t)blk * 64 + row) * D_DIM + lane * 4) = ev;
  }

  double dv = (tx < 64) ? (double)rmin[tx] : 0.0;
  #pragma unroll
  for (int o = 32; o > 0; o >>= 1) dv += __shfl_down(dv, o, 64);
  if (lane == 0) dred[w] = dv;
  __syncthreads();
  if (tx == 0) bsums[blk] = (dred[0] + dred[1]) + (dred[2] + dred[3]);
}

// Lane-parallel exact pair resolution (2 dots/row, numpy-replica); rewrites
// idx (plain) + q row. Sentinel rows (f==1023) left for vq_fixup.
__global__ __launch_bounds__(256) void vq_resolve(
    const float* __restrict__ x, const float* __restrict__ e,
    const float* __restrict__ norms, const unsigned* __restrict__ bitmap,
    float* __restrict__ out_q, float* __restrict__ out_idx) {
  __shared__ float xs[32][257];
  __shared__ int list[64];
  __shared__ int lcount;
  __shared__ int wkf[32];
  const int blk = blockIdx.x, tx = threadIdx.x;
  const int n0 = blk * 64;
  const int lane = tx & 63, w = tx >> 6;
  if (tx == 0) {
    int cnt = 0;
    for (int wi = 0; wi < 2; ++wi) {
      unsigned u = bitmap[blk * 2 + wi];
      while (u) {
        int bit = __ffs(u) - 1;
        list[cnt++] = wi * 32 + bit;
        u &= u - 1;
      }
    }
    lcount = cnt;
  }
  __syncthreads();
  const int nf = lcount;
  if (nf == 0) return;
  const int ri = tx >> 3, dl = tx & 7;

  for (int c0 = 0; c0 < nf; c0 += 32) {
    int R = min(32, nf - c0);
    if (ri < R) {
      int n = n0 + list[c0 + ri];
      int b2 = n >> 11, t2 = n & 2047;
      for (int j = 0; j < 32; ++j) {
        int d = dl * 32 + j;
        xs[ri][d] = x[((size_t)(b2 * 256 + d)) * 2048 + t2];
      }
    }
    __syncthreads();
    if (tx < 64) {
      int pi = tx >> 1, cand = tx & 1;
      float sv = 0.f;
      int ka = 0, kb = 0, n = 0;
      bool act = false;
      if (pi < R) {
        n = n0 + list[c0 + pi];
        int iv = (int)out_idx[n];
        int f = iv >> 10, I = iv & 1023;
        if (f >= 1 && f <= 512) {           // pair row
          act = true;
          int I2 = f - 1;
          ka = min(I, I2); kb = max(I, I2);
          int k = cand ? kb : ka;
          float res[2];
          #pragma unroll
          for (int h = 0; h < 2; ++h) {
            float r8[8];
            #pragma unroll
            for (int j = 0; j < 8; ++j) { float a = xs[pi][h * 128 + j]; r8[j] = __fmul_rn(a, a); }
            for (int i = 8; i < 128; i += 8)
              #pragma unroll
              for (int j = 0; j < 8; ++j) { float a = xs[pi][h * 128 + i + j]; r8[j] = __fadd_rn(r8[j], __fmul_rn(a, a)); }
            res[h] = comb8(r8);
          }
          float xx = __fadd_rn(res[0], res[1]);
          float a = 0.f;
          const float* ep = e + (size_t)k * D_DIM;
          #pragma unroll 4
          for (int d = 0; d < 256; ++d) a = __fmaf_rn(xs[pi][d], ep[d], a);
          float t1 = __fadd_rn(xx, norms[k]);
          sv = t1 - 2.0f * a;
        }
      }
      float so = __shfl_xor(sv, 1, 64);
      if (cand == 0) {
        if (pi < R) {
          if (act) {
            int kf = (so < sv) ? kb : ka;     // tie -> ka (lower)
            out_idx[n] = (float)kf;
            wkf[pi] = kf;
          } else {
            wkf[pi] = -1;                     // sentinel row: fixup's job
          }
        }
      }
    }
    __syncthreads();
    // q-rewrite for resolved rows: wave w handles rows w, w+4, ...
    for (int r = w; r < R; r += 4) {
      int kf = wkf[r];
      if (kf >= 0) {
        int n = n0 + list[c0 + r];
        float4 ev = *(const float4*)(e + (size_t)kf * D_DIM + lane * 4);
        *(float4*)(out_q + (size_t)n * D_DIM + lane * 4) = ev;
      }
    }
    __syncthreads();
  }
}

// Full exact rescan (wave-per-row) for rare sentinel rows; rewrites idx + q.
__global__ __launch_bounds__(64) void vq_fixup(
    const float* __restrict__ x, const float* __restrict__ e,
    const float* __restrict__ norms, const unsigned* __restrict__ bitmap,
    float* __restrict__ out_q, float* __restrict__ out_idx) {
  __shared__ float xrow[256];
  __shared__ float xr16[16];
  const int blk = blockIdx.x, lane = threadIdx.x;
  unsigned long long bm = (unsigned long long)bitmap[blk * 2] |
                          ((unsigned long long)bitmap[blk * 2 + 1] << 32);
  if (!bm) return;
  const int b = blk >> 5, t0 = (blk & 31) * 64;
  while (bm) {
    int row = __ffsll(bm) - 1; bm &= bm - 1;
    int iv = (int)out_idx[(size_t)blk * 64 + row];
    if ((iv >> 10) != 1023) continue;          // resolved pair or plain
    int trow = t0 + row;
    #pragma unroll
    for (int j = 0; j < 4; ++j)
      xrow[lane + 64 * j] = x[((size_t)(b * 256 + lane + 64 * j)) * 2048 + trow];
    asm volatile("s_waitcnt vmcnt(0) lgkmcnt(0)" ::: "memory");
    if (lane < 16) {
      int h = lane >> 3, jj = lane & 7;
      float a0 = xrow[h * 128 + jj];
      float r = __fmul_rn(a0, a0);
      for (int i = 1; i < 16; ++i) {
        float a = xrow[h * 128 + i * 8 + jj];
        r = __fadd_rn(r, __fmul_rn(a, a));
      }
      xr16[lane] = r;
    }
    asm volatile("s_waitcnt lgkmcnt(0)" ::: "memory");
    float xx = __fadd_rn(comb8(&xr16[0]), comb8(&xr16[8]));
    float am[8];
    #pragma unroll
    for (int cc = 0; cc < 8; ++cc) am[cc] = 0.f;
    const float* eb = e + (size_t)(lane * 8) * D_DIM;
    for (int d4 = 0; d4 < 64; ++d4) {
      float4 xv = *(const float4*)&xrow[d4 * 4];
      #pragma unroll
      for (int cc = 0; cc < 8; ++cc) {
        float4 ev = *(const float4*)(eb + (size_t)cc * D_DIM + d4 * 4);
        am[cc] = __fmaf_rn(xv.x, ev.x, am[cc]);
        am[cc] = __fmaf_rn(xv.y, ev.y, am[cc]);
        am[cc] = __fmaf_rn(xv.z, ev.z, am[cc]);
        am[cc] = __fmaf_rn(xv.w, ev.w, am[cc]);
      }
    }
    float lm = 3.4e38f; int lk = 0;
    #pragma unroll
    for (int cc = 0; cc < 8; ++cc) {
      int k = lane * 8 + cc;
      float t1 = __fadd_rn(xx, norms[k]);
      float sv = t1 - 2.0f * am[cc];
      if (sv < lm) { lm = sv; lk = k; }
    }
    #pragma unroll
    for (int off = 1; off < 64; off <<= 1) {
      float om = __shfl_xor(lm, off, 64);
      int oi = __shfl_xor(lk, off, 64);
      if (om < lm || (om == lm && oi < lk)) { lm = om; lk = oi; }
    }
    if (lane == 0) out_idx[(size_t)blk * 64 + row] = (float)lk;
    int wk = __shfl(lk, 0);
    float4 ev = *(const float4*)(e + (size_t)wk * D_DIM + lane * 4);
    *(float4*)(out_q + ((size_t)blk * 64 + row) * D_DIM + lane * 4) = ev;
  }
}

__global__ __launch_bounds__(256) void vq_final(const double* __restrict__ bs,
                                                const double* __restrict__ bs2,
                                                float* __restrict__ out_loss) {
  __shared__ double sred[4];
  int t = threadIdx.x;
  double s = 0.0;
  for (int i = t; i < 2048; i += 256) s += bs[i];
  for (int i = t; i < 512; i += 256) s += bs2[i];
  #pragma unroll
  for (int o = 32; o > 0; o >>= 1) s += __shfl_down(s, o, 64);
  if ((t & 63) == 0) sred[t >> 6] = s;
  __syncthreads();
  if (t == 0)
    out_loss[0] = (float)(0.25 * (((sred[0] + sred[1]) + (sred[2] + sred[3])) / (double)Q_ELEMS));
}

extern "C" void kernel_launch(void* const* d_in, const int* in_sizes, int n_in,
                              void* d_out, int out_size, void* d_ws, size_t ws_size,
                              hipStream_t stream) {
  const float* x = (const float*)d_in[0];
  const float* e = (const float*)d_in[1];
  float* out = (float*)d_out;
  float* out_q = out;
  float* out_loss = out + Q_ELEMS;
  float* out_idx = out + Q_ELEMS + 1;

  char* ws = (char*)d_ws;
  float* norms = (float*)ws;
  double* bsums = (double*)(ws + 2048);
  unsigned* bitmap = (unsigned*)(ws + 20480);
  double* bsums2 = (double*)(ws + 36864);
  unsigned short* e16 = (unsigned short*)(ws + 40960);
  unsigned short* x16 = (unsigned short*)(ws + 303104);

  vq_prep<<<K_CODES, 256, 0, stream>>>(e, norms, e16);
  vq_xpose<<<512, 512, 0, stream>>>(x, x16, bsums2);
  vq_main<<<N_ROWS / 64, 256, 0, stream>>>(norms, e16, x16, e, out_q, out_idx, bsums, bitmap);
  vq_resolve<<<N_ROWS / 64, 256, 0, stream>>>(x, e, norms, bitmap, out_q, out_idx);
  vq_fixup<<<N_ROWS / 64, 64, 0, stream>>>(x, e, norms, bitmap, out_q, out_idx);
  vq_final<<<1, 256, 0, stream>>>(bsums, bsums2, out_loss);
}

// Round 13
// 245.529 us; speedup vs baseline: 2.5408x; 1.6695x over previous
//
#include <hip/hip_runtime.h>
#include <hip/hip_fp16.h>

#define T_DIM 2048
#define D_DIM 256
#define K_CODES 512
#define N_ROWS 131072
#define Q_ELEMS 33554432
#define FMQ 4.0e-4f   // f16-error margin 2e-4 + key-quantization 1.22e-4 + headroom

typedef __attribute__((ext_vector_type(8))) _Float16 f16x8;
typedef __attribute__((ext_vector_type(8))) short s16x8;
typedef __attribute__((ext_vector_type(4))) float f32x4;

// ws layout (bytes) -- proven footprint (rounds 9-12):
// [0, 2048)        norms (512 f32, numpy-pairwise-exact)
// [2048, 18432)    bsums (2048 f64, main loss partials)
// [36864, 40960)   bsums2 (512 f64, xpose sum(x^2) partials)
// [40960, 303104)  e16: f16(512*e), k-granule layout
// [303104, 67411968) x16: f16(x), k-granule per 64-row span
// out_idx[n] self-describing: plain I; pair I+1024*(I2+1); rescan I+1024*1023.

__device__ __forceinline__ float comb8(const float* r) {
  return ((r[0] + r[1]) + (r[2] + r[3])) + ((r[4] + r[5]) + (r[6] + r[7]));
}

// branchless top-3 insert on packed u32 keys (score hi-bits | code lo-9)
__device__ __forceinline__ void ins3(unsigned& m1, unsigned& m2, unsigned& m3, unsigned k) {
  unsigned t1 = max(m1, k); m1 = min(m1, k);
  unsigned t2 = max(m2, t1); m2 = min(m2, t1);
  m3 = min(m3, t2);
}

__device__ __forceinline__ void gl_lds16(const void* g, void* l) {
  __builtin_amdgcn_global_load_lds(
      (const __attribute__((address_space(1))) unsigned int*)g,
      (__attribute__((address_space(3))) unsigned int*)l, 16, 0, 0);
}

__global__ __launch_bounds__(256) void vq_prep(const float* __restrict__ e,
                                               float* __restrict__ norms,
                                               unsigned short* __restrict__ e16) {
  __shared__ float srow[D_DIM];
  int k = blockIdx.x, t = threadIdx.x;
  float v = e[k * D_DIM + t];
  srow[t] = v;
  e16[(k >> 5) * 8192 + (t >> 3) * 256 + (k & 31) * 8 + (t & 7)] =
      __half_as_ushort(__float2half(512.0f * v));
  __syncthreads();
  if (t == 0) {
    float res[2];
    #pragma unroll
    for (int h = 0; h < 2; ++h) {
      float r[8];
      #pragma unroll
      for (int j = 0; j < 8; ++j) { float a = srow[h * 128 + j]; r[j] = __fmul_rn(a, a); }
      for (int i = 8; i < 128; i += 8)
        #pragma unroll
        for (int j = 0; j < 8; ++j) { float a = srow[h * 128 + i + j]; r[j] = __fadd_rn(r[j], __fmul_rn(a, a)); }
      res[h] = comb8(r);
    }
    norms[k] = __fadd_rn(res[0], res[1]);
  }
}

__global__ __launch_bounds__(512, 1) void vq_xpose(const float* __restrict__ x,
                                                   unsigned short* __restrict__ x16,
                                                   double* __restrict__ bsums2) {
  __shared__ unsigned short tlu[32 * 2048];
  __shared__ double dred[8];
  const int tx = threadIdx.x, blk = blockIdx.x;
  const int b = blk >> 3, t0 = (blk & 7) * 256;
  const int w = tx >> 6, lane = tx & 63;

  float xsq = 0.f;
  #pragma unroll
  for (int g8 = 0; g8 < 4; ++g8) {
    unsigned short pk[4][8];
    #pragma unroll
    for (int dj = 0; dj < 8; ++dj) {
      int d = w * 32 + g8 * 8 + dj;
      float4 v = *(const float4*)(x + (size_t)(b * 256 + d) * 2048 + t0 + lane * 4);
      xsq = fmaf(v.x, v.x, xsq); xsq = fmaf(v.y, v.y, xsq);
      xsq = fmaf(v.z, v.z, xsq); xsq = fmaf(v.w, v.w, xsq);
      pk[0][dj] = __half_as_ushort(__float2half(v.x));
      pk[1][dj] = __half_as_ushort(__float2half(v.y));
      pk[2][dj] = __half_as_ushort(__float2half(v.z));
      pk[3][dj] = __half_as_ushort(__float2half(v.w));
    }
    int kg = w * 4 + g8;
    #pragma unroll
    for (int j = 0; j < 4; ++j)
      *(s16x8*)&tlu[kg * 2048 + (lane * 4 + j) * 8] = *(s16x8*)&pk[j][0];
  }
  __syncthreads();
  const size_t obase = (size_t)(b * 2048 + t0) * 256;
  #pragma unroll 4
  for (int i = 0; i < 16; ++i) {
    int q = tx + i * 512;
    s16x8 vv = *(const s16x8*)&tlu[((q >> 6) & 31) * 2048 + ((q >> 11) * 64 + (q & 63)) * 8];
    *(s16x8*)(x16 + obase + (size_t)q * 8) = vv;
  }
  double dv = (double)xsq;
  #pragma unroll
  for (int o = 32; o > 0; o >>= 1) dv += __shfl_down(dv, o, 64);
  if (lane == 0) dred[w] = dv;
  __syncthreads();
  if (tx == 0) {
    double s = 0.0;
    #pragma unroll
    for (int i = 0; i < 8; ++i) s += dred[i];
    bsums2[blk] = s;
  }
}

// T3 schedule (round-11, proven) + branchless packed-key top-3 fold.
__global__ __launch_bounds__(256, 1) void vq_main(
    const float* __restrict__ norms, const unsigned short* __restrict__ e16,
    const unsigned short* __restrict__ x16, const float* __restrict__ e,
    float* __restrict__ out_q, float* __restrict__ out_idx,
    double* __restrict__ bsums) {
  __shared__ unsigned short Bu[2][8192];      // 32 KB: B dbuf; also A staging
  __shared__ float nlds[K_CODES];             // norms[k] + 2.0f
  __shared__ unsigned wredk[2][3][64];
  __shared__ float rmin[64];
  __shared__ int   widx[64];
  __shared__ double dred[4];

  const int tx = threadIdx.x, blk = blockIdx.x;   // 2048 blocks x 64 rows
  const int lane = tx & 63, w = tx >> 6;
  const int wm = w & 1, wn = w >> 1;
  const int c = lane & 15, g = lane >> 4;

  nlds[tx] = norms[tx] + 2.0f;
  nlds[tx + 256] = norms[tx + 256] + 2.0f;

  // stage A through Bu, hoist fragments, hand Bu to B pipeline (round-12 proven)
  #pragma unroll
  for (int i = 0; i < 8; ++i)
    gl_lds16(x16 + (size_t)blk * 16384 + i * 2048 + tx * 8, &Bu[0][0] + i * 2048 + w * 512);
  __syncthreads();
  f16x8 af2[2][8];
  #pragma unroll
  for (int mi = 0; mi < 2; ++mi)
    #pragma unroll
    for (int ch = 0; ch < 8; ++ch)
      af2[mi][ch] = *(const f16x8*)(&Bu[0][0] + (ch * 4 + g) * 512 + (wm * 32 + mi * 16 + c) * 8);
  __syncthreads();
  #pragma unroll
  for (int i = 0; i < 4; ++i)
    gl_lds16(e16 + i * 2048 + tx * 8, &Bu[0][i * 2048 + w * 512]);
  __syncthreads();

  unsigned mk1[8], mk2[8], mk3[8];
  #pragma unroll
  for (int si = 0; si < 8; ++si) { mk1[si] = 0xFFFFFFFFu; mk2[si] = 0xFFFFFFFFu; mk3[si] = 0xFFFFFFFFu; }

  for (int it = 0; it < 16; ++it) {
    if (it < 15) {
      #pragma unroll
      for (int i = 0; i < 4; ++i)
        gl_lds16(e16 + (size_t)(it + 1) * 8192 + i * 2048 + tx * 8,
                 &Bu[(it + 1) & 1][i * 2048 + w * 512]);
    }
    const unsigned short* bb = &Bu[it & 1][0];
    f32x4 acc[2];
    acc[0] = (f32x4){0.f, 0.f, 0.f, 0.f};
    acc[1] = (f32x4){0.f, 0.f, 0.f, 0.f};
    #pragma unroll
    for (int ch = 0; ch < 8; ++ch) {
      f16x8 bf = *(const f16x8*)&bb[(ch * 4 + g) * 256 + (wn * 16 + c) * 8];
      acc[0] = __builtin_amdgcn_mfma_f32_16x16x32_f16(af2[0][ch], bf, acc[0], 0, 0, 0);
      acc[1] = __builtin_amdgcn_mfma_f32_16x16x32_f16(af2[1][ch], bf, acc[1], 0, 0, 0);
    }
    unsigned code = (unsigned)(it * 32 + wn * 16 + c);
    float nrm2 = nlds[code];
    #pragma unroll
    for (int mi = 0; mi < 2; ++mi)
      #pragma unroll
      for (int q = 0; q < 4; ++q) {
        int si = mi * 4 + q;
        float sv2 = fmaf(-0.00390625f, acc[mi][q], nrm2);   // (nrm+2) - 2*dot/512 > 0
        unsigned key = (__float_as_uint(sv2) & 0xFFFFFE00u) | code;
        ins3(mk1[si], mk2[si], mk3[si], key);
      }
    __syncthreads();
  }

  // cross-lane top-3 butterfly on packed keys (16 codes over c)
  #pragma unroll
  for (int si = 0; si < 8; ++si) {
    unsigned a1 = mk1[si], a2 = mk2[si], a3 = mk3[si];
    #pragma unroll
    for (int off = 1; off < 16; off <<= 1) {
      unsigned b1 = (unsigned)__shfl_xor((int)a1, off, 64);
      unsigned b2 = (unsigned)__shfl_xor((int)a2, off, 64);
      unsigned b3 = (unsigned)__shfl_xor((int)a3, off, 64);
      ins3(a1, a2, a3, b1); ins3(a1, a2, a3, b2); ins3(a1, a2, a3, b3);
    }
    if (c == 0) {
      int row = wm * 32 + (si >> 2) * 16 + g * 4 + (si & 3);
      wredk[wn][0][row] = a1; wredk[wn][1][row] = a2; wredk[wn][2][row] = a3;
    }
  }
  __syncthreads();

  if (tx < 64) {
    unsigned a1 = wredk[0][0][tx], a2 = wredk[0][1][tx], a3 = wredk[0][2][tx];
    ins3(a1, a2, a3, wredk[1][0][tx]);
    ins3(a1, a2, a3, wredk[1][1][tx]);
    ins3(a1, a2, a3, wredk[1][2][tx]);
    int I = (int)(a1 & 511u), I2 = (int)(a2 & 511u);
    float s1 = __uint_as_float(a1 & 0xFFFFFE00u);
    float s2 = __uint_as_float(a2 & 0xFFFFFE00u);
    float s3 = __uint_as_float(a3 & 0xFFFFFE00u);
    rmin[tx] = s1 - 2.0f;
    widx[tx] = I;
    bool rescan = (s3 - s1 <= FMQ);
    bool pairf  = (s2 - s1 <= FMQ) && !rescan;
    int enc = I;
    if (pairf)  enc = I + 1024 * (I2 + 1);
    if (rescan) enc = I + 1024 * 1023;
    out_idx[(size_t)blk * 64 + tx] = (float)enc;
  }
  __syncthreads();

  // fused q-write (approx idx; epilogue rewrites flagged rows)
  #pragma unroll 4
  for (int i = 0; i < 16; ++i) {
    int row = w * 16 + i;
    int k = widx[row];
    float4 ev = *(const float4*)(e + (size_t)k * D_DIM + lane * 4);
    *(float4*)(out_q + ((size_t)blk * 64 + row) * D_DIM + lane * 4) = ev;
  }

  double dv = (tx < 64) ? (double)rmin[tx] : 0.0;
  #pragma unroll
  for (int o = 32; o > 0; o >>= 1) dv += __shfl_down(dv, o, 64);
  if (lane == 0) dred[w] = dv;
  __syncthreads();
  if (tx == 0) bsums[blk] = (dred[0] + dred[1]) + (dred[2] + dred[3]);
}

// Unified epilogue: 4 waves/block; each wave handles its share of flagged rows.
// Pairs: 2-lane exact dots (validated rounds 6-12). Rescans: 8-chain full scan
// (validated rounds 6-12). Rewrites idx + q row.
__global__ __launch_bounds__(256) void vq_epilogue(
    const float* __restrict__ x, const float* __restrict__ e,
    const float* __restrict__ norms,
    float* __restrict__ out_q, float* __restrict__ out_idx) {
  __shared__ float xrow[4][256];
  __shared__ float xr16[4][16];
  const int tx = threadIdx.x, blk = blockIdx.x;
  const int lane = tx & 63, w = tx >> 6;

  int iv = (int)out_idx[(size_t)blk * 64 + lane];
  int f = iv >> 10;
  bool flagged = (f != 0);
  unsigned long long bm = __ballot(flagged);
  if (!bm) return;

  int ord = 0;
  while (bm) {
    int row = __ffsll(bm) - 1; bm &= bm - 1;
    if ((ord++ & 3) != w) continue;
    int n = blk * 64 + row;
    int rv = __shfl(iv, row);
    int rf = rv >> 10, I = rv & 1023;
    // load x row (validated fixup pattern)
    int b2 = n >> 11, t2 = n & 2047;
    #pragma unroll
    for (int j = 0; j < 4; ++j)
      xrow[w][lane + 64 * j] = x[((size_t)(b2 * 256 + lane + 64 * j)) * 2048 + t2];
    asm volatile("s_waitcnt vmcnt(0) lgkmcnt(0)" ::: "memory");
    if (lane < 16) {   // exact numpy-pairwise ||x||^2: 16 chains
      int h = lane >> 3, jj = lane & 7;
      float a0 = xrow[w][h * 128 + jj];
      float r = __fmul_rn(a0, a0);
      for (int i = 1; i < 16; ++i) {
        float a = xrow[w][h * 128 + i * 8 + jj];
        r = __fadd_rn(r, __fmul_rn(a, a));
      }
      xr16[w][lane] = r;
    }
    asm volatile("s_waitcnt lgkmcnt(0)" ::: "memory");
    float xx = __fadd_rn(comb8(&xr16[w][0]), comb8(&xr16[w][8]));
    int kf;
    if (rf != 1023) {
      // pair: exact scores for {ka, kb}, lanes 0/1
      int I2 = rf - 1;
      int ka = min(I, I2), kb = max(I, I2);
      float sv = 0.f;
      if (lane < 2) {
        int k = lane ? kb : ka;
        float a = 0.f;
        const float* ep = e + (size_t)k * D_DIM;
        #pragma unroll 4
        for (int d = 0; d < 256; ++d) a = __fmaf_rn(xrow[w][d], ep[d], a);
        float t1 = __fadd_rn(xx, norms[k]);
        sv = t1 - 2.0f * a;
      }
      float s0 = __shfl(sv, 0), s1 = __shfl(sv, 1);
      kf = (s1 < s0) ? kb : ka;            // tie -> ka (lower)
    } else {
      // full exact rescan: 8 sequential chains per lane (codes ascending)
      float am[8];
      #pragma unroll
      for (int cc = 0; cc < 8; ++cc) am[cc] = 0.f;
      const float* eb = e + (size_t)(lane * 8) * D_DIM;
      for (int d4 = 0; d4 < 64; ++d4) {
        float4 xv = *(const float4*)&xrow[w][d4 * 4];
        #pragma unroll
        for (int cc = 0; cc < 8; ++cc) {
          float4 ev = *(const float4*)(eb + (size_t)cc * D_DIM + d4 * 4);
          am[cc] = __fmaf_rn(xv.x, ev.x, am[cc]);
          am[cc] = __fmaf_rn(xv.y, ev.y, am[cc]);
          am[cc] = __fmaf_rn(xv.z, ev.z, am[cc]);
          am[cc] = __fmaf_rn(xv.w, ev.w, am[cc]);
        }
      }
      float lm = 3.4e38f; int lk = 0;
      #pragma unroll
      for (int cc = 0; cc < 8; ++cc) {
        int k = lane * 8 + cc;
        float t1 = __fadd_rn(xx, norms[k]);
        float sv = t1 - 2.0f * am[cc];
        if (sv < lm) { lm = sv; lk = k; }
      }
      #pragma unroll
      for (int off = 1; off < 64; off <<= 1) {
        float om = __shfl_xor(lm, off, 64);
        int oi = __shfl_xor(lk, off, 64);
        if (om < lm || (om == lm && oi < lk)) { lm = om; lk = oi; }
      }
      kf = lk;
    }
    if (lane == 0) out_idx[n] = (float)kf;
    float4 ev = *(const float4*)(e + (size_t)kf * D_DIM + lane * 4);
    *(float4*)(out_q + (size_t)n * D_DIM + lane * 4) = ev;
  }
}

__global__ __launch_bounds__(256) void vq_final(const double* __restrict__ bs,
                                                const double* __restrict__ bs2,
                                                float* __restrict__ out_loss) {
  __shared__ double sred[4];
  int t = threadIdx.x;
  double s = 0.0;
  for (int i = t; i < 2048; i += 256) s += bs[i];
  for (int i = t; i < 512; i += 256) s += bs2[i];
  #pragma unroll
  for (int o = 32; o > 0; o >>= 1) s += __shfl_down(s, o, 64);
  if ((t & 63) == 0) sred[t >> 6] = s;
  __syncthreads();
  if (t == 0)
    out_loss[0] = (float)(0.25 * (((sred[0] + sred[1]) + (sred[2] + sred[3])) / (double)Q_ELEMS));
}

extern "C" void kernel_launch(void* const* d_in, const int* in_sizes, int n_in,
                              void* d_out, int out_size, void* d_ws, size_t ws_size,
                              hipStream_t stream) {
  const float* x = (const float*)d_in[0];
  const float* e = (const float*)d_in[1];
  float* out = (float*)d_out;
  float* out_q = out;
  float* out_loss = out + Q_ELEMS;
  float* out_idx = out + Q_ELEMS + 1;

  char* ws = (char*)d_ws;
  float* norms = (float*)ws;
  double* bsums = (double*)(ws + 2048);
  double* bsums2 = (double*)(ws + 36864);
  unsigned short* e16 = (unsigned short*)(ws + 40960);
  unsigned short* x16 = (unsigned short*)(ws + 303104);

  vq_prep<<<K_CODES, 256, 0, stream>>>(e, norms, e16);
  vq_xpose<<<512, 512, 0, stream>>>(x, x16, bsums2);
  vq_main<<<N_ROWS / 64, 256, 0, stream>>>(norms, e16, x16, e, out_q, out_idx, bsums);
  vq_epilogue<<<N_ROWS / 64, 256, 0, stream>>>(x, e, norms, out_q, out_idx);
  vq_final<<<1, 256, 0, stream>>>(bsums, bsums2, out_loss);
}

// Round 14
// 186.207 us; speedup vs baseline: 3.3502x; 1.3186x over previous
//
#include <hip/hip_runtime.h>
#include <hip/hip_fp16.h>

#define T_DIM 2048
#define D_DIM 256
#define K_CODES 512
#define N_ROWS 131072
#define Q_ELEMS 33554432
#define FMQ_FIX 60000u   // 2.235e-4 * 2^28: f16-err margin (proven r6-8) + headroom

typedef __attribute__((ext_vector_type(8))) _Float16 f16x8;
typedef __attribute__((ext_vector_type(8))) short s16x8;
typedef __attribute__((ext_vector_type(4))) float f32x4;

// ws layout (bytes) -- proven footprint (rounds 9-13):
// [0, 2048)        norms (512 f32, numpy-pairwise-exact)
// [2048, 18432)    bsums (2048 f64, main loss partials)
// [36864, 40960)   bsums2 (512 f64, xpose sum(x^2) partials)
// [40960, 303104)  e16: f16(512*e), k-granule layout
// [303104, 67411968) x16: f16(x), k-granule per 64-row span
// out_idx[n] self-describing: plain I; pair I+1024*(I2+1); rescan I+1024*1023.

__device__ __forceinline__ float comb8(const float* r) {
  return ((r[0] + r[1]) + (r[2] + r[3])) + ((r[4] + r[5]) + (r[6] + r[7]));
}

// branchless top-3 insert on packed u32 keys (fixed-point score | code lo-9)
__device__ __forceinline__ void ins3(unsigned& m1, unsigned& m2, unsigned& m3, unsigned k) {
  unsigned t1 = max(m1, k); m1 = min(m1, k);
  unsigned t2 = max(m2, t1); m2 = min(m2, t1);
  m3 = min(m3, t2);
}

__device__ __forceinline__ void gl_lds16(const void* g, void* l) {
  __builtin_amdgcn_global_load_lds(
      (const __attribute__((address_space(1))) unsigned int*)g,
      (__attribute__((address_space(3))) unsigned int*)l, 16, 0, 0);
}

__global__ __launch_bounds__(256) void vq_prep(const float* __restrict__ e,
                                               float* __restrict__ norms,
                                               unsigned short* __restrict__ e16) {
  __shared__ float srow[D_DIM];
  int k = blockIdx.x, t = threadIdx.x;
  float v = e[k * D_DIM + t];
  srow[t] = v;
  e16[(k >> 5) * 8192 + (t >> 3) * 256 + (k & 31) * 8 + (t & 7)] =
      __half_as_ushort(__float2half(512.0f * v));
  __syncthreads();
  if (t == 0) {
    float res[2];
    #pragma unroll
    for (int h = 0; h < 2; ++h) {
      float r[8];
      #pragma unroll
      for (int j = 0; j < 8; ++j) { float a = srow[h * 128 + j]; r[j] = __fmul_rn(a, a); }
      for (int i = 8; i < 128; i += 8)
        #pragma unroll
        for (int j = 0; j < 8; ++j) { float a = srow[h * 128 + i + j]; r[j] = __fadd_rn(r[j], __fmul_rn(a, a)); }
      res[h] = comb8(r);
    }
    norms[k] = __fadd_rn(res[0], res[1]);
  }
}

__global__ __launch_bounds__(512, 1) void vq_xpose(const float* __restrict__ x,
                                                   unsigned short* __restrict__ x16,
                                                   double* __restrict__ bsums2) {
  __shared__ unsigned short tlu[32 * 2048];
  __shared__ double dred[8];
  const int tx = threadIdx.x, blk = blockIdx.x;
  const int b = blk >> 3, t0 = (blk & 7) * 256;
  const int w = tx >> 6, lane = tx & 63;

  float xsq = 0.f;
  #pragma unroll
  for (int g8 = 0; g8 < 4; ++g8) {
    unsigned short pk[4][8];
    #pragma unroll
    for (int dj = 0; dj < 8; ++dj) {
      int d = w * 32 + g8 * 8 + dj;
      float4 v = *(const float4*)(x + (size_t)(b * 256 + d) * 2048 + t0 + lane * 4);
      xsq = fmaf(v.x, v.x, xsq); xsq = fmaf(v.y, v.y, xsq);
      xsq = fmaf(v.z, v.z, xsq); xsq = fmaf(v.w, v.w, xsq);
      pk[0][dj] = __half_as_ushort(__float2half(v.x));
      pk[1][dj] = __half_as_ushort(__float2half(v.y));
      pk[2][dj] = __half_as_ushort(__float2half(v.z));
      pk[3][dj] = __half_as_ushort(__float2half(v.w));
    }
    int kg = w * 4 + g8;
    #pragma unroll
    for (int j = 0; j < 4; ++j)
      *(s16x8*)&tlu[kg * 2048 + (lane * 4 + j) * 8] = *(s16x8*)&pk[j][0];
  }
  __syncthreads();
  const size_t obase = (size_t)(b * 2048 + t0) * 256;
  #pragma unroll 4
  for (int i = 0; i < 16; ++i) {
    int q = tx + i * 512;
    s16x8 vv = *(const s16x8*)&tlu[((q >> 6) & 31) * 2048 + ((q >> 11) * 64 + (q & 63)) * 8];
    *(s16x8*)(x16 + obase + (size_t)q * 8) = vv;
  }
  double dv = (double)xsq;
  #pragma unroll
  for (int o = 32; o > 0; o >>= 1) dv += __shfl_down(dv, o, 64);
  if (lane == 0) dred[w] = dv;
  __syncthreads();
  if (tx == 0) {
    double s = 0.0;
    #pragma unroll
    for (int i = 0; i < 8; ++i) s += dred[i];
    bsums2[blk] = s;
  }
}

// T3 schedule (r11) + branchless FIXED-POINT packed-key top-3 fold (r13+r14).
__global__ __launch_bounds__(256, 1) void vq_main(
    const float* __restrict__ norms, const unsigned short* __restrict__ e16,
    const unsigned short* __restrict__ x16, const float* __restrict__ e,
    float* __restrict__ out_q, float* __restrict__ out_idx,
    double* __restrict__ bsums) {
  __shared__ unsigned short Bu[2][8192];      // 32 KB: B dbuf; also A staging
  __shared__ float nlds[K_CODES];             // (norms[k]+2) * 2^28
  __shared__ unsigned wredk[2][3][64];
  __shared__ float rmin[64];
  __shared__ int   widx[64];
  __shared__ double dred[4];

  const int tx = threadIdx.x, blk = blockIdx.x;   // 2048 blocks x 64 rows
  const int lane = tx & 63, w = tx >> 6;
  const int wm = w & 1, wn = w >> 1;
  const int c = lane & 15, g = lane >> 4;

  nlds[tx] = (norms[tx] + 2.0f) * 268435456.0f;
  nlds[tx + 256] = (norms[tx + 256] + 2.0f) * 268435456.0f;

  // stage A through Bu, hoist fragments, hand Bu to B pipeline (proven r11-13)
  #pragma unroll
  for (int i = 0; i < 8; ++i)
    gl_lds16(x16 + (size_t)blk * 16384 + i * 2048 + tx * 8, &Bu[0][0] + i * 2048 + w * 512);
  __syncthreads();
  f16x8 af2[2][8];
  #pragma unroll
  for (int mi = 0; mi < 2; ++mi)
    #pragma unroll
    for (int ch = 0; ch < 8; ++ch)
      af2[mi][ch] = *(const f16x8*)(&Bu[0][0] + (ch * 4 + g) * 512 + (wm * 32 + mi * 16 + c) * 8);
  __syncthreads();
  #pragma unroll
  for (int i = 0; i < 4; ++i)
    gl_lds16(e16 + i * 2048 + tx * 8, &Bu[0][i * 2048 + w * 512]);
  __syncthreads();

  unsigned mk1[8], mk2[8], mk3[8];
  #pragma unroll
  for (int si = 0; si < 8; ++si) { mk1[si] = 0xFFFFFFFFu; mk2[si] = 0xFFFFFFFFu; mk3[si] = 0xFFFFFFFFu; }

  for (int it = 0; it < 16; ++it) {
    if (it < 15) {
      #pragma unroll
      for (int i = 0; i < 4; ++i)
        gl_lds16(e16 + (size_t)(it + 1) * 8192 + i * 2048 + tx * 8,
                 &Bu[(it + 1) & 1][i * 2048 + w * 512]);
    }
    const unsigned short* bb = &Bu[it & 1][0];
    f32x4 acc[2];
    acc[0] = (f32x4){0.f, 0.f, 0.f, 0.f};
    acc[1] = (f32x4){0.f, 0.f, 0.f, 0.f};
    #pragma unroll
    for (int ch = 0; ch < 8; ++ch) {
      f16x8 bf = *(const f16x8*)&bb[(ch * 4 + g) * 256 + (wn * 16 + c) * 8];
      acc[0] = __builtin_amdgcn_mfma_f32_16x16x32_f16(af2[0][ch], bf, acc[0], 0, 0, 0);
      acc[1] = __builtin_amdgcn_mfma_f32_16x16x32_f16(af2[1][ch], bf, acc[1], 0, 0, 0);
    }
    unsigned code = (unsigned)(it * 32 + wn * 16 + c);
    float nrmS = nlds[code];
    #pragma unroll
    for (int mi = 0; mi < 2; ++mi)
      #pragma unroll
      for (int q = 0; q < 4; ++q) {
        int si = mi * 4 + q;
        // ((nrm+2) - 2*dot/512) * 2^28, as one fma; >0 always (sv2 in [0.6,3.4])
        float svf = fmaf(-1048576.0f, acc[mi][q], nrmS);
        unsigned key = ((unsigned)svf & 0xFFFFFE00u) | code;
        ins3(mk1[si], mk2[si], mk3[si], key);
      }
    __syncthreads();
  }

  // cross-lane top-3 butterfly on packed keys (16 codes over c)
  #pragma unroll
  for (int si = 0; si < 8; ++si) {
    unsigned a1 = mk1[si], a2 = mk2[si], a3 = mk3[si];
    #pragma unroll
    for (int off = 1; off < 16; off <<= 1) {
      unsigned b1 = (unsigned)__shfl_xor((int)a1, off, 64);
      unsigned b2 = (unsigned)__shfl_xor((int)a2, off, 64);
      unsigned b3 = (unsigned)__shfl_xor((int)a3, off, 64);
      ins3(a1, a2, a3, b1); ins3(a1, a2, a3, b2); ins3(a1, a2, a3, b3);
    }
    if (c == 0) {
      int row = wm * 32 + (si >> 2) * 16 + g * 4 + (si & 3);
      wredk[wn][0][row] = a1; wredk[wn][1][row] = a2; wredk[wn][2][row] = a3;
    }
  }
  __syncthreads();

  if (tx < 64) {
    unsigned a1 = wredk[0][0][tx], a2 = wredk[0][1][tx], a3 = wredk[0][2][tx];
    ins3(a1, a2, a3, wredk[1][0][tx]);
    ins3(a1, a2, a3, wredk[1][1][tx]);
    ins3(a1, a2, a3, wredk[1][2][tx]);
    int I = (int)(a1 & 511u), I2 = (int)(a2 & 511u);
    unsigned s1 = a1 & 0xFFFFFE00u, s2 = a2 & 0xFFFFFE00u, s3 = a3 & 0xFFFFFE00u;
    rmin[tx] = (float)s1 * 3.7252903e-9f - 2.0f;   // /2^28 - 2
    widx[tx] = I;
    bool rescan = (s3 - s1 <= FMQ_FIX);
    bool pairf  = (s2 - s1 <= FMQ_FIX) && !rescan;
    int enc = I;
    if (pairf)  enc = I + 1024 * (I2 + 1);
    if (rescan) enc = I + 1024 * 1023;
    out_idx[(size_t)blk * 64 + tx] = (float)enc;
  }
  __syncthreads();

  // fused q-write (approx idx; epilogue rewrites flagged rows)
  #pragma unroll 4
  for (int i = 0; i < 16; ++i) {
    int row = w * 16 + i;
    int k = widx[row];
    float4 ev = *(const float4*)(e + (size_t)k * D_DIM + lane * 4);
    *(float4*)(out_q + ((size_t)blk * 64 + row) * D_DIM + lane * 4) = ev;
  }

  double dv = (tx < 64) ? (double)rmin[tx] : 0.0;
  #pragma unroll
  for (int o = 32; o > 0; o >>= 1) dv += __shfl_down(dv, o, 64);
  if (lane == 0) dred[w] = dv;
  __syncthreads();
  if (tx == 0) bsums[blk] = (dred[0] + dred[1]) + (dred[2] + dred[3]);
}

// Unified epilogue. KEY r14 fix: candidate e rows are STAGED INTO LDS with
// coalesced float4 loads BEFORE the exact dependent-FMA chains (r13 read e
// from global inside the chain: ~14k cycles/row, 145 us total).
__global__ __launch_bounds__(256) void vq_epilogue(
    const float* __restrict__ x, const float* __restrict__ e,
    const float* __restrict__ norms,
    float* __restrict__ out_q, float* __restrict__ out_idx) {
  __shared__ float xrow[4][256];
  __shared__ float xr16[4][16];
  __shared__ float epair[4][2][256];
  const int tx = threadIdx.x, blk = blockIdx.x;
  const int lane = tx & 63, w = tx >> 6;

  int iv = (int)out_idx[(size_t)blk * 64 + lane];
  int f = iv >> 10;
  unsigned long long bm = __ballot(f != 0);
  if (!bm) return;

  int ord = 0;
  while (bm) {
    int row = __ffsll(bm) - 1; bm &= bm - 1;
    if ((ord++ & 3) != w) continue;
    int n = blk * 64 + row;
    int rv = __shfl(iv, row);
    int rf = rv >> 10, I = rv & 1023;
    int b2 = n >> 11, t2 = n & 2047;
    // load x row (scattered, unavoidable) + candidate e rows (coalesced)
    #pragma unroll
    for (int j = 0; j < 4; ++j)
      xrow[w][lane + 64 * j] = x[((size_t)(b2 * 256 + lane + 64 * j)) * 2048 + t2];
    int ka = 0, kb = 0;
    if (rf != 1023) {
      int I2 = rf - 1;
      ka = min(I, I2); kb = max(I, I2);
      float4 e0 = *(const float4*)(e + (size_t)ka * D_DIM + lane * 4);
      float4 e1 = *(const float4*)(e + (size_t)kb * D_DIM + lane * 4);
      *(float4*)&epair[w][0][lane * 4] = e0;
      *(float4*)&epair[w][1][lane * 4] = e1;
    }
    asm volatile("s_waitcnt vmcnt(0) lgkmcnt(0)" ::: "memory");
    if (lane < 16) {   // exact numpy-pairwise ||x||^2: 16 chains
      int h = lane >> 3, jj = lane & 7;
      float a0 = xrow[w][h * 128 + jj];
      float r = __fmul_rn(a0, a0);
      for (int i = 1; i < 16; ++i) {
        float a = xrow[w][h * 128 + i * 8 + jj];
        r = __fadd_rn(r, __fmul_rn(a, a));
      }
      xr16[w][lane] = r;
    }
    asm volatile("s_waitcnt lgkmcnt(0)" ::: "memory");
    float xx = __fadd_rn(comb8(&xr16[w][0]), comb8(&xr16[w][8]));
    int kf;
    if (rf != 1023) {
      // pair: exact scores via LDS-operand chains, lanes 0/1
      float sv = 0.f;
      if (lane < 2) {
        const float* ep = &epair[w][lane][0];
        const float* xr = &xrow[w][0];
        float a = 0.f;
        #pragma unroll 16
        for (int d = 0; d < 256; ++d) a = __fmaf_rn(xr[d], ep[d], a);
        int k = lane ? kb : ka;
        float t1 = __fadd_rn(xx, norms[k]);
        sv = t1 - 2.0f * a;
      }
      float s0 = __shfl(sv, 0), s1 = __shfl(sv, 1);
      kf = (s1 < s0) ? kb : ka;            // tie -> ka (lower)
    } else {
      // rare full exact rescan: 8 sequential chains per lane (codes ascending)
      float am[8];
      #pragma unroll
      for (int cc = 0; cc < 8; ++cc) am[cc] = 0.f;
      const float* eb = e + (size_t)(lane * 8) * D_DIM;
      for (int d4 = 0; d4 < 64; ++d4) {
        float4 xv = *(const float4*)&xrow[w][d4 * 4];
        #pragma unroll
        for (int cc = 0; cc < 8; ++cc) {
          float4 ev = *(const float4*)(eb + (size_t)cc * D_DIM + d4 * 4);
          am[cc] = __fmaf_rn(xv.x, ev.x, am[cc]);
          am[cc] = __fmaf_rn(xv.y, ev.y, am[cc]);
          am[cc] = __fmaf_rn(xv.z, ev.z, am[cc]);
          am[cc] = __fmaf_rn(xv.w, ev.w, am[cc]);
        }
      }
      float lm = 3.4e38f; int lk = 0;
      #pragma unroll
      for (int cc = 0; cc < 8; ++cc) {
        int k = lane * 8 + cc;
        float t1 = __fadd_rn(xx, norms[k]);
        float sv = t1 - 2.0f * am[cc];
        if (sv < lm) { lm = sv; lk = k; }
      }
      #pragma unroll
      for (int off = 1; off < 64; off <<= 1) {
        float om = __shfl_xor(lm, off, 64);
        int oi = __shfl_xor(lk, off, 64);
        if (om < lm || (om == lm && oi < lk)) { lm = om; lk = oi; }
      }
      kf = lk;
    }
    if (lane == 0) out_idx[n] = (float)kf;
    float4 ev = *(const float4*)(e + (size_t)kf * D_DIM + lane * 4);
    *(float4*)(out_q + (size_t)n * D_DIM + lane * 4) = ev;
  }
}

__global__ __launch_bounds__(256) void vq_final(const double* __restrict__ bs,
                                                const double* __restrict__ bs2,
                                                float* __restrict__ out_loss) {
  __shared__ double sred[4];
  int t = threadIdx.x;
  double s = 0.0;
  for (int i = t; i < 2048; i += 256) s += bs[i];
  for (int i = t; i < 512; i += 256) s += bs2[i];
  #pragma unroll
  for (int o = 32; o > 0; o >>= 1) s += __shfl_down(s, o, 64);
  if ((t & 63) == 0) sred[t >> 6] = s;
  __syncthreads();
  if (t == 0)
    out_loss[0] = (float)(0.25 * (((sred[0] + sred[1]) + (sred[2] + sred[3])) / (double)Q_ELEMS));
}

extern "C" void kernel_launch(void* const* d_in, const int* in_sizes, int n_in,
                              void* d_out, int out_size, void* d_ws, size_t ws_size,
                              hipStream_t stream) {
  const float* x = (const float*)d_in[0];
  const float* e = (const float*)d_in[1];
  float* out = (float*)d_out;
  float* out_q = out;
  float* out_loss = out + Q_ELEMS;
  float* out_idx = out + Q_ELEMS + 1;

  char* ws = (char*)d_ws;
  float* norms = (float*)ws;
  double* bsums = (double*)(ws + 2048);
  double* bsums2 = (double*)(ws + 36864);
  unsigned short* e16 = (unsigned short*)(ws + 40960);
  unsigned short* x16 = (unsigned short*)(ws + 303104);

  vq_prep<<<K_CODES, 256, 0, stream>>>(e, norms, e16);
  vq_xpose<<<512, 512, 0, stream>>>(x, x16, bsums2);
  vq_main<<<N_ROWS / 64, 256, 0, stream>>>(norms, e16, x16, e, out_q, out_idx, bsums);
  vq_epilogue<<<N_ROWS / 64, 256, 0, stream>>>(x, e, norms, out_q, out_idx);
  vq_final<<<1, 256, 0, stream>>>(bsums, bsums2, out_loss);
}